// Round 5
// baseline (699.683 us; speedup 1.0000x reference)
//
#include <hip/hip_runtime.h>
#include <hip/hip_bf16.h>

// adLIF: Wx = x @ W^T (fp32 FMA GEMM, strictly sequential-K accumulation to
// mirror BLAS bit-for-bit), then sequential LIF scan over T with rounding-exact
// fp32 ops. Input dtype (fp32 vs bf16) detected ON DEVICE from x's bit pattern.
// r15 GEMM: index-swapped DOUBLE BUFFER, single compute body. r11's dbuf blew
//   VGPR (200) because the 2x-unrolled body doubled live ranges; here the
//   buffer is picked by (i&1)*BUFSZ with the outer loop unroll(disable) so the
//   body is never cloned -> VGPR ~ r6's 116. ONE barrier per 16-k tile (was 2);
//   the serial ds_write segment between the old barrier pair now overlaps
//   compute across waves. k-order/arithmetic unchanged -> bit-exact.
//   Cached C-stores kept (exact r11 conditions for the scan's L3 regime).
// r15 scan: r11 code restored VERBATIM (best measured ~138 us): ring[4][8]
//   loads, sdat[2][8] payload rotation, pst[4][8] full-pointer rotation,
//   grouped stores. r12/r13/r14 "improvements" all regressed to ~200 us.

#define M_SZ 65536  // B*T
#define H_SZ 512
#define K_SZ 512
#define B_SZ 128
#define T_SZ 512
#define LSTR 132  // LDS row stride (dwords), %32==4: staging writes conflict-free
#define BUFSZ (16 * LSTR)  // dwords per LDS tile buffer (8448 B)

typedef __attribute__((ext_vector_type(4))) float f32x4;

__device__ __forceinline__ bool detect_bf16(const unsigned int* __restrict__ w) {
  int c = 0;
#pragma unroll
  for (int i = 0; i < 64; ++i) {
    unsigned int e = (w[i] >> 7) & 0xffu;
    c += (e >= 115u && e <= 131u) ? 1 : 0;
  }
  return c > 32;  // bf16 exponents cluster in [115,131]; fp32 mantissa bits don't
}

template <bool ISB>
__device__ __forceinline__ f32x4 ld4t(const void* __restrict__ p, size_t off) {
  if constexpr (!ISB) {
    return *reinterpret_cast<const f32x4*>(reinterpret_cast<const float*>(p) + off);
  } else {
    uint2 v = *reinterpret_cast<const uint2*>(reinterpret_cast<const unsigned short*>(p) + off);
    f32x4 r;
    r.x = __uint_as_float((v.x & 0xffffu) << 16);
    r.y = __uint_as_float(v.x & 0xffff0000u);
    r.z = __uint_as_float((v.y & 0xffffu) << 16);
    r.w = __uint_as_float(v.y & 0xffff0000u);
    return r;
  }
}

template <bool ISB>
__device__ __forceinline__ float ld1t(const void* __restrict__ p, int i) {
  if constexpr (!ISB) return reinterpret_cast<const float*>(p)[i];
  return __uint_as_float((unsigned int)(reinterpret_cast<const unsigned short*>(p)[i]) << 16);
}

// ---------------- GEMM: C[m][n] = sum_k X[m][k]*W[n][k], fp32, k ascending ----
template <bool ISB>
__device__ __forceinline__ void gemm_body(const void* __restrict__ X,
                                          const void* __restrict__ Wm,
                                          float* __restrict__ C,
                                          float* __restrict__ As,
                                          float* __restrict__ Bs) {
  const int tid = threadIdx.x;
  const int r0 = tid >> 2;       // 0..63: staged row
  const int q0 = (tid & 3) * 4;  // 0,4,8,12: k-group
  const int tx = tid & 15;       // n-group
  const int ty = tid >> 4;       // m-group
  const size_t M0 = (size_t)(blockIdx.x >> 2) * 128;
  const int N0 = (blockIdx.x & 3) * 128;

  float acc[8][8];
#pragma unroll
  for (int i = 0; i < 8; ++i)
#pragma unroll
    for (int j = 0; j < 8; ++j) acc[i][j] = 0.0f;

  const size_t aoff0 = (M0 + r0) * K_SZ + q0;
  const size_t aoff1 = (M0 + r0 + 64) * K_SZ + q0;
  const size_t boff0 = (size_t)(N0 + r0) * K_SZ + q0;
  const size_t boff1 = (size_t)(N0 + r0 + 64) * K_SZ + q0;

  f32x4 pa0, pa1, pb0, pb1;  // prefetch regs; stage consumes, prefetch refills

  auto prefetch = [&](int kk) {
    pa0 = ld4t<ISB>(X, aoff0 + kk);
    pa1 = ld4t<ISB>(X, aoff1 + kk);
    pb0 = ld4t<ISB>(Wm, boff0 + kk);
    pb1 = ld4t<ISB>(Wm, boff1 + kk);
  };
  auto stage = [&](float* __restrict__ A, float* __restrict__ B) {
    A[(q0 + 0) * LSTR + r0] = pa0.x; A[(q0 + 1) * LSTR + r0] = pa0.y;
    A[(q0 + 2) * LSTR + r0] = pa0.z; A[(q0 + 3) * LSTR + r0] = pa0.w;
    A[(q0 + 0) * LSTR + r0 + 64] = pa1.x; A[(q0 + 1) * LSTR + r0 + 64] = pa1.y;
    A[(q0 + 2) * LSTR + r0 + 64] = pa1.z; A[(q0 + 3) * LSTR + r0 + 64] = pa1.w;
    B[(q0 + 0) * LSTR + r0] = pb0.x; B[(q0 + 1) * LSTR + r0] = pb0.y;
    B[(q0 + 2) * LSTR + r0] = pb0.z; B[(q0 + 3) * LSTR + r0] = pb0.w;
    B[(q0 + 0) * LSTR + r0 + 64] = pb1.x; B[(q0 + 1) * LSTR + r0 + 64] = pb1.y;
    B[(q0 + 2) * LSTR + r0 + 64] = pb1.z; B[(q0 + 3) * LSTR + r0 + 64] = pb1.w;
  };
  auto compute = [&](const float* __restrict__ A, const float* __restrict__ B) {
#pragma unroll
    for (int k = 0; k < 16; ++k) {
      const f32x4 a0 = *reinterpret_cast<const f32x4*>(A + k * LSTR + ty * 4);
      const f32x4 a1 = *reinterpret_cast<const f32x4*>(A + k * LSTR + 64 + ty * 4);
      const f32x4 b0 = *reinterpret_cast<const f32x4*>(B + k * LSTR + tx * 4);
      const f32x4 b1 = *reinterpret_cast<const f32x4*>(B + k * LSTR + 64 + tx * 4);
      const float avv[8] = {a0.x, a0.y, a0.z, a0.w, a1.x, a1.y, a1.z, a1.w};
      const float bvv[8] = {b0.x, b0.y, b0.z, b0.w, b1.x, b1.y, b1.z, b1.w};
#pragma unroll
      for (int i = 0; i < 8; ++i)
#pragma unroll
        for (int j = 0; j < 8; ++j) acc[i][j] += avv[i] * bvv[j];  // contracts to FMA
    }
  };

  // Prologue: buf0 <- tile 0; regs <- tile 1. (32 tiles of 16 k.)
  prefetch(0);
  stage(As, Bs);   // buffer 0
  prefetch(16);

  // Per iter i: [barrier] [stage tile i+1 -> buf (i+1)&1] [prefetch tile i+2]
  //             [compute tile i from buf i&1]
  // Hazards: barrier(i) guarantees every wave finished iter i-1, including
  // compute from buf[(i+1)&1] -> staging it is safe. No wave can be 2 iters
  // ahead (it would block at barrier(i+1)). Single body, runtime parity:
  // unroll(disable) prevents the r11 live-range doubling (VGPR 200 cliff).
#pragma clang loop unroll(disable)
  for (int i = 0; i < 32; ++i) {
    __syncthreads();
    const int cb = (i & 1) * BUFSZ;
    const int nb = ((i + 1) & 1) * BUFSZ;
    if (i + 1 < 32) {
      stage(As + nb, Bs + nb);          // overlaps other waves' compute
      if (i + 2 < 32) prefetch(16 * (i + 2));
    }
    compute(As + cb, Bs + cb);
  }

#pragma unroll
  for (int r = 0; r < 8; ++r) {
    const size_t m = M0 + ((r < 4) ? (ty * 4 + r) : (64 + ty * 4 + (r - 4)));
    float* Cp = C + m * H_SZ + N0;
    f32x4 v0 = {acc[r][0], acc[r][1], acc[r][2], acc[r][3]};
    f32x4 v1 = {acc[r][4], acc[r][5], acc[r][6], acc[r][7]};
    // plain (cached) stores: Wx stays L3-resident for the scan (r11 conditions)
    *reinterpret_cast<f32x4*>(Cp + tx * 4) = v0;
    *reinterpret_cast<f32x4*>(Cp + 64 + tx * 4) = v1;
  }
}

__global__ __launch_bounds__(256) void sgemm_bt(const void* __restrict__ X,
                                                const void* __restrict__ Wm,
                                                float* __restrict__ C) {
  __shared__ float As[2 * BUFSZ];  // 16.9 KB: double-buffered A tiles
  __shared__ float Bs[2 * BUFSZ];  // 16.9 KB: double-buffered B tiles
  if (detect_bf16(reinterpret_cast<const unsigned int*>(X)))
    gemm_body<true>(X, Wm, C, As, Bs);
  else
    gemm_body<false>(X, Wm, C, As, Bs);
}

// ---------------- LIF scan: r11 code VERBATIM (best measured ~138 us) -------
// 1024 blocks x 64 thr; block = (b, 64-h strip), lane = h. Chunk = 8 t; each
// t-row load is one coalesced 256 B global_load_dword (wave-uniform t).
// ring[4][8]: load lookahead 3 chunks (RAW wait distance ~48 vmem ops).
// sdat[2][8]: store payloads, overwritten 2 chunks after their store issues.
// pst[4][8]:  store addresses (full pointers -> the regs ARE the vaddr pair),
//             pst[(c+2)&3] recomputed at end of phase c -> WAR distance ~48.
#define SCT 8             // timesteps per chunk
#define SNC (T_SZ / SCT)  // 64 chunks

template <bool ISB>
__device__ __forceinline__ void scan_body(
    const float* __restrict__ wx, const void* __restrict__ alpha_p,
    const void* __restrict__ beta_p, const void* __restrict__ a_p,
    const void* __restrict__ b_p, const void* __restrict__ u0p,
    const void* __restrict__ w0p, const void* __restrict__ s0p,
    void* __restrict__ out) {
  const int lane = threadIdx.x;  // 0..63 = h within strip
  const int b = blockIdx.x >> 3;
  const int h = (blockIdx.x & 7) * 64 + lane;

  const float al = fminf(fmaxf(ld1t<ISB>(alpha_p, h), (float)0.8187307530779818),
                         (float)0.9607894391523232);
  const float be = fminf(fmaxf(ld1t<ISB>(beta_p, h), (float)0.9672161004820059),
                         (float)0.9917013044213351);
  const float av = fminf(fmaxf(ld1t<ISB>(a_p, h), -1.0f), 1.0f);
  const float bv = fminf(fmaxf(ld1t<ISB>(b_p, h), 0.0f), 2.0f);
  const float om = __fsub_rn(1.0f, al);

  const int bh = b * H_SZ + h;
  float u = ld1t<ISB>(u0p, bh);
  float w = ld1t<ISB>(w0p, bh);
  float s = ld1t<ISB>(s0p, bh);

  const float* xb = wx + (size_t)b * T_SZ * H_SZ + h;  // + t*H (lane folded in)
  char* ob = reinterpret_cast<char*>(out);
  const size_t ob0 = (size_t)b * T_SZ * H_SZ + h;
  const size_t esz = ISB ? 2u : 4u;

  float ring[4][SCT];
  auto loadc = [&](float* dst, int c) {
#pragma unroll
    for (int j = 0; j < SCT; ++j) {
      int t = c * SCT + j;
      t = (t < T_SZ) ? t : (T_SZ - 1);  // wave-uniform clamp, branchless
      dst[j] = xb[(size_t)t * H_SZ];
    }
  };

  float sdat[2][SCT];  // store payload rotation (2 chunks deep)
  char* pst[4][SCT];   // store address rotation (4 chunks deep)
  auto calca = [&](char** dst, int c) {
#pragma unroll
    for (int j = 0; j < SCT; ++j)
      dst[j] = ob + (ob0 + (size_t)(c * SCT + j) * H_SZ) * esz;  // OOB ptrs never deref'd
  };

  loadc(ring[0], 0); loadc(ring[1], 1); loadc(ring[2], 2); loadc(ring[3], 3);
  calca(pst[0], 0); calca(pst[1], 1); calca(pst[2], 2); calca(pst[3], 3);

  for (int c0 = 0; c0 < SNC; c0 += 4) {
#pragma unroll
    for (int p = 0; p < 4; ++p) {  // static phase index -> static registers
      const int c = c0 + p;        // chunk; c & 3 == p
      const int q = p & 1;
#pragma unroll
      for (int j = 0; j < SCT; ++j) {
        const float cur = ring[p][j];
        // numpy left-to-right, each op individually rounded (no FMA contraction)
        w = __fadd_rn(__fadd_rn(__fmul_rn(be, w), __fmul_rn(av, u)), __fmul_rn(bv, s));
        u = __fadd_rn(__fmul_rn(al, __fsub_rn(u, s)), __fmul_rn(om, __fsub_rn(cur, w)));
        const bool sp = (u > 1.0f);
        s = sp ? 1.0f : 0.0f;
        // payload: fp32 spike value, or bf16 bit pattern (0x3F80/0) by select
        sdat[q][j] = ISB ? __uint_as_float(sp ? 0x3F80u : 0u) : s;
      }
      // grouped stores; data regs rotate 2 chunks, addr regs rotate 4 chunks
#pragma unroll
      for (int j = 0; j < SCT; ++j) {
        if constexpr (ISB)
          *reinterpret_cast<unsigned short*>(pst[p][j]) =
              (unsigned short)__float_as_uint(sdat[q][j]);
        else
          *reinterpret_cast<float*>(pst[p][j]) = sdat[q][j];
      }
      loadc(ring[p], c + 4);           // refill just-consumed phase (clamped past T)
      calca(pst[(p + 2) & 3], c + 2);  // rewrite addrs used 2 chunks ago, for chunk c+2
    }
  }
}

__global__ __launch_bounds__(64) void lif_scan(
    const float* __restrict__ wx, const void* __restrict__ X,
    const void* __restrict__ alpha_p, const void* __restrict__ beta_p,
    const void* __restrict__ a_p, const void* __restrict__ b_p,
    const void* __restrict__ u0p, const void* __restrict__ w0p,
    const void* __restrict__ s0p, void* __restrict__ out) {
  if (detect_bf16(reinterpret_cast<const unsigned int*>(X)))
    scan_body<true>(wx, alpha_p, beta_p, a_p, b_p, u0p, w0p, s0p, out);
  else
    scan_body<false>(wx, alpha_p, beta_p, a_p, b_p, u0p, w0p, s0p, out);
}

extern "C" void kernel_launch(void* const* d_in, const int* in_sizes, int n_in,
                              void* d_out, int out_size, void* d_ws, size_t ws_size,
                              hipStream_t stream) {
  const void* X = d_in[0];   // x [B,T,I]
  const void* Wm = d_in[1];  // W [H,I]
  float* ws = reinterpret_cast<float*>(d_ws);  // Wx fp32 [B,T,H]

  sgemm_bt<<<dim3((M_SZ / 128) * (H_SZ / 128)), dim3(256), 0, stream>>>(X, Wm, ws);

  lif_scan<<<dim3(B_SZ * 8), dim3(64), 0, stream>>>(
      ws, X, d_in[2], d_in[3], d_in[4], d_in[5], d_in[6], d_in[7], d_in[8], d_out);
}

// Round 6
// 616.882 us; speedup vs baseline: 1.1342x; 1.1342x over previous
//
#include <hip/hip_runtime.h>
#include <hip/hip_bf16.h>

// adLIF: Wx = x @ W^T (fp32 FMA GEMM, strictly sequential-K accumulation to
// mirror BLAS bit-for-bit), then sequential LIF scan over T with rounding-exact
// fp32 ops. Input dtype (fp32 vs bf16) detected ON DEVICE from x's bit pattern.
// r16 = best-known COMPOSITION, zero new code:
//   GEMM: r6 single-buffer structure VERBATIM (VGPR 116, 418-420 us w/ cached
//     C-stores). Double-buffer attempts r11 (VGPR 200, 620 us) and r15
//     (VGPR 144, 554 us) both crossed the 128-VGPR occupancy cliff -> RULE:
//     no dbuf on this kernel; keep VGPR <= 128.
//   scan: r11 ring/sdat/pst code VERBATIM (138-145 us, reproduced twice).
//     r12 (ring8), r13 (persistent loffs), r14 (producer-consumer) all ~200 us.
// Next queued probe: k-tile 32 single-buffer (halves barriers; +16 VGPR risk).

#define M_SZ 65536  // B*T
#define H_SZ 512
#define K_SZ 512
#define B_SZ 128
#define T_SZ 512
#define LSTR 132  // LDS row stride (dwords), %32==4: staging writes conflict-free

typedef __attribute__((ext_vector_type(4))) float f32x4;

__device__ __forceinline__ bool detect_bf16(const unsigned int* __restrict__ w) {
  int c = 0;
#pragma unroll
  for (int i = 0; i < 64; ++i) {
    unsigned int e = (w[i] >> 7) & 0xffu;
    c += (e >= 115u && e <= 131u) ? 1 : 0;
  }
  return c > 32;  // bf16 exponents cluster in [115,131]; fp32 mantissa bits don't
}

template <bool ISB>
__device__ __forceinline__ f32x4 ld4t(const void* __restrict__ p, size_t off) {
  if constexpr (!ISB) {
    return *reinterpret_cast<const f32x4*>(reinterpret_cast<const float*>(p) + off);
  } else {
    uint2 v = *reinterpret_cast<const uint2*>(reinterpret_cast<const unsigned short*>(p) + off);
    f32x4 r;
    r.x = __uint_as_float((v.x & 0xffffu) << 16);
    r.y = __uint_as_float(v.x & 0xffff0000u);
    r.z = __uint_as_float((v.y & 0xffffu) << 16);
    r.w = __uint_as_float(v.y & 0xffff0000u);
    return r;
  }
}

template <bool ISB>
__device__ __forceinline__ float ld1t(const void* __restrict__ p, int i) {
  if constexpr (!ISB) return reinterpret_cast<const float*>(p)[i];
  return __uint_as_float((unsigned int)(reinterpret_cast<const unsigned short*>(p)[i]) << 16);
}

// ---------------- GEMM: C[m][n] = sum_k X[m][k]*W[n][k], fp32, k ascending ----
template <bool ISB>
__device__ __forceinline__ void gemm_body(const void* __restrict__ X,
                                          const void* __restrict__ Wm,
                                          float* __restrict__ C,
                                          float* __restrict__ As,
                                          float* __restrict__ Bs) {
  const int tid = threadIdx.x;
  const int r0 = tid >> 2;       // 0..63: staged row
  const int q0 = (tid & 3) * 4;  // 0,4,8,12: k-group
  const int tx = tid & 15;       // n-group
  const int ty = tid >> 4;       // m-group
  const size_t M0 = (size_t)(blockIdx.x >> 2) * 128;
  const int N0 = (blockIdx.x & 3) * 128;

  float acc[8][8];
#pragma unroll
  for (int i = 0; i < 8; ++i)
#pragma unroll
    for (int j = 0; j < 8; ++j) acc[i][j] = 0.0f;

  const size_t aoff0 = (M0 + r0) * K_SZ + q0;
  const size_t aoff1 = (M0 + r0 + 64) * K_SZ + q0;
  const size_t boff0 = (size_t)(N0 + r0) * K_SZ + q0;
  const size_t boff1 = (size_t)(N0 + r0 + 64) * K_SZ + q0;

  f32x4 pa0 = ld4t<ISB>(X, aoff0), pa1 = ld4t<ISB>(X, aoff1);
  f32x4 pb0 = ld4t<ISB>(Wm, boff0), pb1 = ld4t<ISB>(Wm, boff1);

  for (int kk = 0; kk < K_SZ; kk += 16) {
    __syncthreads();  // prior compute done -> LDS free
    As[(q0 + 0) * LSTR + r0] = pa0.x; As[(q0 + 1) * LSTR + r0] = pa0.y;
    As[(q0 + 2) * LSTR + r0] = pa0.z; As[(q0 + 3) * LSTR + r0] = pa0.w;
    As[(q0 + 0) * LSTR + r0 + 64] = pa1.x; As[(q0 + 1) * LSTR + r0 + 64] = pa1.y;
    As[(q0 + 2) * LSTR + r0 + 64] = pa1.z; As[(q0 + 3) * LSTR + r0 + 64] = pa1.w;
    Bs[(q0 + 0) * LSTR + r0] = pb0.x; Bs[(q0 + 1) * LSTR + r0] = pb0.y;
    Bs[(q0 + 2) * LSTR + r0] = pb0.z; Bs[(q0 + 3) * LSTR + r0] = pb0.w;
    Bs[(q0 + 0) * LSTR + r0 + 64] = pb1.x; Bs[(q0 + 1) * LSTR + r0 + 64] = pb1.y;
    Bs[(q0 + 2) * LSTR + r0 + 64] = pb1.z; Bs[(q0 + 3) * LSTR + r0 + 64] = pb1.w;
    __syncthreads();  // tile ready
    if (kk + 16 < K_SZ) {  // prefetch next chunk; in flight across compute
      pa0 = ld4t<ISB>(X, aoff0 + kk + 16); pa1 = ld4t<ISB>(X, aoff1 + kk + 16);
      pb0 = ld4t<ISB>(Wm, boff0 + kk + 16); pb1 = ld4t<ISB>(Wm, boff1 + kk + 16);
    }
#pragma unroll
    for (int k = 0; k < 16; ++k) {
      const f32x4 a0 = *reinterpret_cast<const f32x4*>(As + k * LSTR + ty * 4);
      const f32x4 a1 = *reinterpret_cast<const f32x4*>(As + k * LSTR + 64 + ty * 4);
      const f32x4 b0 = *reinterpret_cast<const f32x4*>(Bs + k * LSTR + tx * 4);
      const f32x4 b1 = *reinterpret_cast<const f32x4*>(Bs + k * LSTR + 64 + tx * 4);
      const float av[8] = {a0.x, a0.y, a0.z, a0.w, a1.x, a1.y, a1.z, a1.w};
      const float bv[8] = {b0.x, b0.y, b0.z, b0.w, b1.x, b1.y, b1.z, b1.w};
#pragma unroll
      for (int i = 0; i < 8; ++i)
#pragma unroll
        for (int j = 0; j < 8; ++j) acc[i][j] += av[i] * bv[j];  // contracts to FMA
    }
  }

#pragma unroll
  for (int r = 0; r < 8; ++r) {
    const size_t m = M0 + ((r < 4) ? (ty * 4 + r) : (64 + ty * 4 + (r - 4)));
    float* Cp = C + m * H_SZ + N0;
    f32x4 v0 = {acc[r][0], acc[r][1], acc[r][2], acc[r][3]};
    f32x4 v1 = {acc[r][4], acc[r][5], acc[r][6], acc[r][7]};
    // plain (cached) stores: Wx stays L3-resident for the scan (r11 conditions)
    *reinterpret_cast<f32x4*>(Cp + tx * 4) = v0;
    *reinterpret_cast<f32x4*>(Cp + 64 + tx * 4) = v1;
  }
}

__global__ __launch_bounds__(256) void sgemm_bt(const void* __restrict__ X,
                                                const void* __restrict__ Wm,
                                                float* __restrict__ C) {
  __shared__ float As[16 * LSTR];  // 8.45 KB
  __shared__ float Bs[16 * LSTR];  // 8.45 KB
  if (detect_bf16(reinterpret_cast<const unsigned int*>(X)))
    gemm_body<true>(X, Wm, C, As, Bs);
  else
    gemm_body<false>(X, Wm, C, As, Bs);
}

// ---------------- LIF scan: r11 code VERBATIM (best measured 138-145 us) ----
// 1024 blocks x 64 thr; block = (b, 64-h strip), lane = h. Chunk = 8 t; each
// t-row load is one coalesced 256 B global_load_dword (wave-uniform t).
// ring[4][8]: load lookahead 3 chunks (RAW wait distance ~48 vmem ops).
// sdat[2][8]: store payloads, overwritten 2 chunks after their store issues.
// pst[4][8]:  store addresses (full pointers -> the regs ARE the vaddr pair),
//             pst[(c+2)&3] recomputed at end of phase c -> WAR distance ~48.
#define SCT 8             // timesteps per chunk
#define SNC (T_SZ / SCT)  // 64 chunks

template <bool ISB>
__device__ __forceinline__ void scan_body(
    const float* __restrict__ wx, const void* __restrict__ alpha_p,
    const void* __restrict__ beta_p, const void* __restrict__ a_p,
    const void* __restrict__ b_p, const void* __restrict__ u0p,
    const void* __restrict__ w0p, const void* __restrict__ s0p,
    void* __restrict__ out) {
  const int lane = threadIdx.x;  // 0..63 = h within strip
  const int b = blockIdx.x >> 3;
  const int h = (blockIdx.x & 7) * 64 + lane;

  const float al = fminf(fmaxf(ld1t<ISB>(alpha_p, h), (float)0.8187307530779818),
                         (float)0.9607894391523232);
  const float be = fminf(fmaxf(ld1t<ISB>(beta_p, h), (float)0.9672161004820059),
                         (float)0.9917013044213351);
  const float av = fminf(fmaxf(ld1t<ISB>(a_p, h), -1.0f), 1.0f);
  const float bv = fminf(fmaxf(ld1t<ISB>(b_p, h), 0.0f), 2.0f);
  const float om = __fsub_rn(1.0f, al);

  const int bh = b * H_SZ + h;
  float u = ld1t<ISB>(u0p, bh);
  float w = ld1t<ISB>(w0p, bh);
  float s = ld1t<ISB>(s0p, bh);

  const float* xb = wx + (size_t)b * T_SZ * H_SZ + h;  // + t*H (lane folded in)
  char* ob = reinterpret_cast<char*>(out);
  const size_t ob0 = (size_t)b * T_SZ * H_SZ + h;
  const size_t esz = ISB ? 2u : 4u;

  float ring[4][SCT];
  auto loadc = [&](float* dst, int c) {
#pragma unroll
    for (int j = 0; j < SCT; ++j) {
      int t = c * SCT + j;
      t = (t < T_SZ) ? t : (T_SZ - 1);  // wave-uniform clamp, branchless
      dst[j] = xb[(size_t)t * H_SZ];
    }
  };

  float sdat[2][SCT];  // store payload rotation (2 chunks deep)
  char* pst[4][SCT];   // store address rotation (4 chunks deep)
  auto calca = [&](char** dst, int c) {
#pragma unroll
    for (int j = 0; j < SCT; ++j)
      dst[j] = ob + (ob0 + (size_t)(c * SCT + j) * H_SZ) * esz;  // OOB ptrs never deref'd
  };

  loadc(ring[0], 0); loadc(ring[1], 1); loadc(ring[2], 2); loadc(ring[3], 3);
  calca(pst[0], 0); calca(pst[1], 1); calca(pst[2], 2); calca(pst[3], 3);

  for (int c0 = 0; c0 < SNC; c0 += 4) {
#pragma unroll
    for (int p = 0; p < 4; ++p) {  // static phase index -> static registers
      const int c = c0 + p;        // chunk; c & 3 == p
      const int q = p & 1;
#pragma unroll
      for (int j = 0; j < SCT; ++j) {
        const float cur = ring[p][j];
        // numpy left-to-right, each op individually rounded (no FMA contraction)
        w = __fadd_rn(__fadd_rn(__fmul_rn(be, w), __fmul_rn(av, u)), __fmul_rn(bv, s));
        u = __fadd_rn(__fmul_rn(al, __fsub_rn(u, s)), __fmul_rn(om, __fsub_rn(cur, w)));
        const bool sp = (u > 1.0f);
        s = sp ? 1.0f : 0.0f;
        // payload: fp32 spike value, or bf16 bit pattern (0x3F80/0) by select
        sdat[q][j] = ISB ? __uint_as_float(sp ? 0x3F80u : 0u) : s;
      }
      // grouped stores; data regs rotate 2 chunks, addr regs rotate 4 chunks
#pragma unroll
      for (int j = 0; j < SCT; ++j) {
        if constexpr (ISB)
          *reinterpret_cast<unsigned short*>(pst[p][j]) =
              (unsigned short)__float_as_uint(sdat[q][j]);
        else
          *reinterpret_cast<float*>(pst[p][j]) = sdat[q][j];
      }
      loadc(ring[p], c + 4);           // refill just-consumed phase (clamped past T)
      calca(pst[(p + 2) & 3], c + 2);  // rewrite addrs used 2 chunks ago, for chunk c+2
    }
  }
}

__global__ __launch_bounds__(64) void lif_scan(
    const float* __restrict__ wx, const void* __restrict__ X,
    const void* __restrict__ alpha_p, const void* __restrict__ beta_p,
    const void* __restrict__ a_p, const void* __restrict__ b_p,
    const void* __restrict__ u0p, const void* __restrict__ w0p,
    const void* __restrict__ s0p, void* __restrict__ out) {
  if (detect_bf16(reinterpret_cast<const unsigned int*>(X)))
    scan_body<true>(wx, alpha_p, beta_p, a_p, b_p, u0p, w0p, s0p, out);
  else
    scan_body<false>(wx, alpha_p, beta_p, a_p, b_p, u0p, w0p, s0p, out);
}

extern "C" void kernel_launch(void* const* d_in, const int* in_sizes, int n_in,
                              void* d_out, int out_size, void* d_ws, size_t ws_size,
                              hipStream_t stream) {
  const void* X = d_in[0];   // x [B,T,I]
  const void* Wm = d_in[1];  // W [H,I]
  float* ws = reinterpret_cast<float*>(d_ws);  // Wx fp32 [B,T,H]

  sgemm_bt<<<dim3((M_SZ / 128) * (H_SZ / 128)), dim3(256), 0, stream>>>(X, Wm, ws);

  lif_scan<<<dim3(B_SZ * 8), dim3(64), 0, stream>>>(
      ws, X, d_in[2], d_in[3], d_in[4], d_in[5], d_in[6], d_in[7], d_in[8], d_out);
}